// Round 1
// baseline (491.982 us; speedup 1.0000x reference)
//
#include <hip/hip_runtime.h>
#include <math.h>

// VQ-VAE quantize: z [32,8,16,16] f32, codebook [16384,8] f32
// N=8192 rows, K=16384 codes, D=8.
// Outputs (concatenated f32): z_q [65536], loss [1], idx-as-float [8192].
//
// flat[n,k] = -100*d[n,k] = 200*dot(z_n,e_k) + a_n + b_k
//   a_n = -100*||z_n||^2, b_k = -100*||e_k||^2
// softmax over k at T=0.01 -> exp underflows to 0 unless flat-m > -87, so
// guard exp: only candidates near the min ever execute exp/div.

#define NROWS 8192
#define KCODES 16384

// ---------------- prep: transpose z to [n][8] ----------------
__global__ __launch_bounds__(256) void prep_z(const float* __restrict__ z,
                                              float* __restrict__ zt) {
    int n = blockIdx.x * 256 + threadIdx.x;     // 0..8191
    int b = n >> 8, hw = n & 255;
    const float* zp = z + b * 2048 + hw;        // z[b][c][hw], c stride 256
    float4 v0, v1;
    v0.x = zp[0 * 256]; v0.y = zp[1 * 256]; v0.z = zp[2 * 256]; v0.w = zp[3 * 256];
    v1.x = zp[4 * 256]; v1.y = zp[5 * 256]; v1.z = zp[6 * 256]; v1.w = zp[7 * 256];
    float4* o = (float4*)(zt + n * 8);
    o[0] = v0; o[1] = v1;
}

// ---------------- prep: codebook norms ----------------
__global__ __launch_bounds__(256) void prep_cb(const float* __restrict__ cb,
                                               float* __restrict__ bk) {
    int k = blockIdx.x * 256 + threadIdx.x;     // 0..16383
    const float4* c4 = (const float4*)cb;
    float4 c0 = c4[2 * k], c1 = c4[2 * k + 1];
    float nrm = c0.x * c0.x + c0.y * c0.y + c0.z * c0.z + c0.w * c0.w
              + c1.x * c1.x + c1.y * c1.y + c1.z * c1.z + c1.w * c1.w;
    bk[k] = -100.0f * nrm;
}

// ---------------- pass 1: per-row online softmax + argmin ----------------
// 1 wave handles 8 rows; each lane strides K by 64. Online (m,s,t) with
// guarded exp; butterfly merge across 64 lanes at the end.
__global__ __launch_bounds__(256) void pass1(
    const float* __restrict__ cb, const float* __restrict__ bk,
    const float* __restrict__ zt,
    float* __restrict__ am_out, float* __restrict__ s_out,
    float* __restrict__ out_zq, float* __restrict__ out_idx,
    float* __restrict__ scal)  // scal[0]=sum(zq-z)^2, scal[1]=sum(t/s-log s)
{
    const int wave = threadIdx.x >> 6;
    const int lane = threadIdx.x & 63;
    const int row0 = (blockIdx.x * 4 + wave) * 8;

    float zr[8][8];
    float a[8];
#pragma unroll
    for (int r = 0; r < 8; ++r) {
        const float4* p = (const float4*)(zt + (row0 + r) * 8);  // wave-uniform: broadcast
        float4 v0 = p[0], v1 = p[1];
        zr[r][0] = v0.x; zr[r][1] = v0.y; zr[r][2] = v0.z; zr[r][3] = v0.w;
        zr[r][4] = v1.x; zr[r][5] = v1.y; zr[r][6] = v1.z; zr[r][7] = v1.w;
        float nn = 0.f;
#pragma unroll
        for (int c = 0; c < 8; ++c) nn += zr[r][c] * zr[r][c];
        a[r] = -100.0f * nn;
    }

    const float4* c4 = (const float4*)cb;
    float m[8], s[8], t[8];
    int id[8];
    {   // init with k = lane
        int k = lane;
        float4 c0 = c4[2 * k], c1 = c4[2 * k + 1];
        float b = bk[k];
#pragma unroll
        for (int r = 0; r < 8; ++r) {
            float dot = zr[r][0] * c0.x + zr[r][1] * c0.y + zr[r][2] * c0.z + zr[r][3] * c0.w
                      + zr[r][4] * c1.x + zr[r][5] * c1.y + zr[r][6] * c1.z + zr[r][7] * c1.w;
            m[r] = fmaf(dot, 200.0f, a[r] + b);
            s[r] = 1.0f; t[r] = 0.0f; id[r] = k;
        }
    }
    for (int k = lane + 64; k < KCODES; k += 64) {
        float4 c0 = c4[2 * k], c1 = c4[2 * k + 1];
        float b = bk[k];
#pragma unroll
        for (int r = 0; r < 8; ++r) {
            float dot = zr[r][0] * c0.x + zr[r][1] * c0.y + zr[r][2] * c0.z + zr[r][3] * c0.w
                      + zr[r][4] * c1.x + zr[r][5] * c1.y + zr[r][6] * c1.z + zr[r][7] * c1.w;
            float flat = fmaf(dot, 200.0f, a[r] + b);
            float x = flat - m[r];
            if (x > 0.0f) {              // new max: rescale (rare after warmup)
                float f = expf(-x);
                t[r] = f * fmaf(-x, s[r], t[r]);
                s[r] = fmaf(s[r], f, 1.0f);
                m[r] = flat; id[r] = k;
            } else if (x > -87.0f) {     // non-underflowing candidate (rare)
                float e = expf(x);
                s[r] += e;
                t[r] = fmaf(x, e, t[r]);
            }
        }
    }

    float entAcc = 0.0f, sqAcc = 0.0f;
#pragma unroll
    for (int r = 0; r < 8; ++r) {
        float mr = m[r], sr = s[r], tr = t[r];
        int ir = id[r];
        for (int off = 32; off > 0; off >>= 1) {
            float mo = __shfl_xor(mr, off);
            float so = __shfl_xor(sr, off);
            float to = __shfl_xor(tr, off);
            int   io = __shfl_xor(ir, off);
            float mn = fmaxf(mr, mo);
            float d1 = mr - mn, d2 = mo - mn;
            float f1 = expf(d1), f2 = expf(d2);   // one of them is exp(0)=1
            float tn = f1 * fmaf(d1, sr, tr) + f2 * fmaf(d2, so, to);
            float sn = f1 * sr + f2 * so;
            ir = (mr > mo) ? ir : ((mo > mr) ? io : (ir < io ? ir : io));
            mr = mn; sr = sn; tr = tn;
        }
        if (lane == 0) {
            int row = row0 + r;
            entAcc += tr / sr - logf(sr);
            am_out[row] = a[r] - mr;
            s_out[row]  = sr;
            out_idx[row] = (float)ir;
            float4 q0 = c4[2 * ir], q1 = c4[2 * ir + 1];
            float qv[8] = {q0.x, q0.y, q0.z, q0.w, q1.x, q1.y, q1.z, q1.w};
            int bb = row >> 8, hw = row & 255;
            float* o = out_zq + bb * 2048 + hw;
#pragma unroll
            for (int c = 0; c < 8; ++c) {
                o[c * 256] = qv[c];
                float dq = qv[c] - zr[r][c];
                sqAcc += dq * dq;
            }
        }
    }
    if (lane == 0) {
        atomicAdd(&scal[0], sqAcc);
        atomicAdd(&scal[1], entAcc);
    }
}

// ---------------- pass 2: avg_probs, k-major ----------------
// thread owns one k; rows staged 512 at a time in LDS (broadcast reads).
__global__ __launch_bounds__(256) void pass2(
    const float* __restrict__ cb, const float* __restrict__ bk,
    const float* __restrict__ zt, const float* __restrict__ am,
    const float* __restrict__ sarr, float* __restrict__ avgp)
{
    __shared__ float lz[512 * 8];
    __shared__ float lam[512];
    __shared__ float lsv[512];
    const int tid = threadIdx.x;
    const int kb = blockIdx.x & 63;
    const int rs = blockIdx.x >> 6;          // 16 row splits
    const int row0 = rs * 512;
    const int k = kb * 256 + tid;

    const float4* zsrc = (const float4*)(zt + row0 * 8);
    float4* zdst = (float4*)lz;
#pragma unroll
    for (int i = 0; i < 4; ++i) zdst[tid + 256 * i] = zsrc[tid + 256 * i];
    for (int i = tid; i < 512; i += 256) { lam[i] = am[row0 + i]; lsv[i] = sarr[row0 + i]; }
    __syncthreads();

    const float4* c4 = (const float4*)cb;
    float4 c0 = c4[2 * k], c1 = c4[2 * k + 1];
    float b = bk[k];
    float acc = 0.0f;
#pragma unroll 4
    for (int n = 0; n < 512; ++n) {
        const float4* zp = (const float4*)(lz + n * 8);   // broadcast, conflict-free
        float4 v0 = zp[0], v1 = zp[1];
        float dot = v0.x * c0.x + v0.y * c0.y + v0.z * c0.z + v0.w * c0.w
                  + v1.x * c1.x + v1.y * c1.y + v1.z * c1.z + v1.w * c1.w;
        float x = fmaf(dot, 200.0f, lam[n] + b);          // flat - m_n
        if (x > -87.0f) acc += expf(x) / lsv[n];          // rare
    }
    atomicAdd(&avgp[k], acc);
}

// ---------------- finalize: avg entropy + loss assembly ----------------
__global__ __launch_bounds__(256) void finalize(
    const float* __restrict__ avgp, const float* __restrict__ scal,
    float* __restrict__ out_loss)
{
    float acc = 0.0f;
    for (int k = threadIdx.x; k < KCODES; k += 256) {
        float avg = avgp[k] * (1.0f / 8192.0f);
        acc += avg * logf(avg + 1e-5f);    // avg==0 contributes exactly 0
    }
#pragma unroll
    for (int off = 32; off > 0; off >>= 1) acc += __shfl_xor(acc, off);
    __shared__ float red[4];
    int wave = threadIdx.x >> 6, lane = threadIdx.x & 63;
    if (lane == 0) red[wave] = acc;
    __syncthreads();
    if (threadIdx.x == 0) {
        float T = red[0] + red[1] + red[2] + red[3];   // sum avg*log(avg+eps)
        // loss = 1.25*mean((zq-z)^2) + 0.1*(sample_entropy - avg_entropy)
        //      = 1.25*sq/65536 + 0.1*(-entS/8192 + T)
        float loss = 1.25f * (scal[0] * (1.0f / 65536.0f))
                   + 0.1f * (T - scal[1] * (1.0f / 8192.0f));
        out_loss[0] = loss;
    }
}

extern "C" void kernel_launch(void* const* d_in, const int* in_sizes, int n_in,
                              void* d_out, int out_size, void* d_ws, size_t ws_size,
                              hipStream_t stream) {
    const float* z  = (const float*)d_in[0];   // [32,8,16,16]
    const float* cb = (const float*)d_in[1];   // [16384,8]
    float* out = (float*)d_out;
    float* ws  = (float*)d_ws;

    // workspace layout (floats)
    float* zt   = ws;                // 65536  : z transposed [n][8]
    float* am   = ws + 65536;        // 8192   : a_n - m_n
    float* sarr = ws + 73728;        // 8192   : softmax denom s_n
    float* bk   = ws + 81920;        // 16384  : -100*||e_k||^2
    float* avgp = ws + 98304;        // 16384  : sum_n p[n,k]
    float* scal = ws + 114688;       // 2      : [sq, entS]

    float* out_zq   = out;           // 65536
    float* out_loss = out + 65536;   // 1
    float* out_idx  = out + 65537;   // 8192

    // ws is re-poisoned to 0xAA before every launch -> zero accumulators
    hipMemsetAsync(avgp, 0, (16384 + 2) * sizeof(float), stream);

    prep_z <<<32,   256, 0, stream>>>(z, zt);
    prep_cb<<<64,   256, 0, stream>>>(cb, bk);
    pass1  <<<256,  256, 0, stream>>>(cb, bk, zt, am, sarr, out_zq, out_idx, scal);
    pass2  <<<1024, 256, 0, stream>>>(cb, bk, zt, am, sarr, avgp);
    finalize<<<1,   256, 0, stream>>>(avgp, scal, out_loss);
}

// Round 2
// 273.258 us; speedup vs baseline: 1.8004x; 1.8004x over previous
//
#include <hip/hip_runtime.h>
#include <math.h>

// VQ-VAE quantize: z [32,8,16,16] f32, codebook [16384,8] f32
// N=8192 rows, K=16384 codes, D=8.
// Outputs (concatenated f32): z_q [65536], loss [1], idx-as-float [8192].
//
// flat[n,k] = -100*d[n,k]; softmax over k at T=0.01. Shift-invariance lets us
// drop the per-row norm a_n in the hot loop: track m' = max_k(200*dot+b_k),
// x = (200*dot+b) - m'. exp underflows below -87 -> guard (rare).
//
// R1 lesson: 8 rows/wave spilled (VGPR_Count=84 < ~100 live) -> 2.6GB scratch
// traffic at 11% occupancy. Now 2 rows/wave (~47 live regs), 1024 blocks.

#define NROWS 8192
#define KCODES 16384

__device__ __forceinline__ float dot8(const float* zr, float4 c0, float4 c1) {
    return zr[0] * c0.x + zr[1] * c0.y + zr[2] * c0.z + zr[3] * c0.w
         + zr[4] * c1.x + zr[5] * c1.y + zr[6] * c1.z + zr[7] * c1.w;
}

// ---------------- prep: transpose z to [n][8] ----------------
__global__ __launch_bounds__(256) void prep_z(const float* __restrict__ z,
                                              float* __restrict__ zt) {
    int n = blockIdx.x * 256 + threadIdx.x;     // 0..8191
    int b = n >> 8, hw = n & 255;
    const float* zp = z + b * 2048 + hw;        // z[b][c][hw], c stride 256
    float4 v0, v1;
    v0.x = zp[0 * 256]; v0.y = zp[1 * 256]; v0.z = zp[2 * 256]; v0.w = zp[3 * 256];
    v1.x = zp[4 * 256]; v1.y = zp[5 * 256]; v1.z = zp[6 * 256]; v1.w = zp[7 * 256];
    float4* o = (float4*)(zt + n * 8);
    o[0] = v0; o[1] = v1;
}

// ---------------- prep: codebook norms ----------------
__global__ __launch_bounds__(256) void prep_cb(const float* __restrict__ cb,
                                               float* __restrict__ bk) {
    int k = blockIdx.x * 256 + threadIdx.x;     // 0..16383
    const float4* c4 = (const float4*)cb;
    float4 c0 = c4[2 * k], c1 = c4[2 * k + 1];
    float nrm = c0.x * c0.x + c0.y * c0.y + c0.z * c0.z + c0.w * c0.w
              + c1.x * c1.x + c1.y * c1.y + c1.z * c1.z + c1.w * c1.w;
    bk[k] = -100.0f * nrm;
}

// ---------------- pass 1: per-row online softmax + argmin ----------------
// 1 wave handles 2 rows; each lane strides K by 64. Online (m,s,t) with
// guarded exp; butterfly merge across 64 lanes at the end.
__global__ __launch_bounds__(256) void pass1(
    const float* __restrict__ cb, const float* __restrict__ bk,
    const float* __restrict__ zt,
    float* __restrict__ am_out, float* __restrict__ rs_out,
    float* __restrict__ out_zq, float* __restrict__ out_idx,
    float* __restrict__ scal)  // scal[0]=sum(zq-z)^2, scal[1]=sum(t/s-log s)
{
    const int wave = threadIdx.x >> 6;
    const int lane = threadIdx.x & 63;
    const int row0 = (blockIdx.x * 4 + wave) * 2;

    float z0[8], z1[8];
    {
        const float4* p = (const float4*)(zt + row0 * 8);  // wave-uniform
        float4 a0 = p[0], a1 = p[1], b0 = p[2], b1 = p[3];
        z0[0] = a0.x; z0[1] = a0.y; z0[2] = a0.z; z0[3] = a0.w;
        z0[4] = a1.x; z0[5] = a1.y; z0[6] = a1.z; z0[7] = a1.w;
        z1[0] = b0.x; z1[1] = b0.y; z1[2] = b0.z; z1[3] = b0.w;
        z1[4] = b1.x; z1[5] = b1.y; z1[6] = b1.z; z1[7] = b1.w;
    }

    const float4* c4 = (const float4*)cb;
    float m0, m1, sv0, sv1, t0, t1;
    int i0, i1;
    {   // init with k = lane
        int k = lane;
        float4 c0 = c4[2 * k], c1 = c4[2 * k + 1];
        float b = bk[k];
        m0 = fmaf(dot8(z0, c0, c1), 200.0f, b);
        m1 = fmaf(dot8(z1, c0, c1), 200.0f, b);
        sv0 = 1.0f; t0 = 0.0f; i0 = k;
        sv1 = 1.0f; t1 = 0.0f; i1 = k;
    }
#pragma unroll 2
    for (int k = lane + 64; k < KCODES; k += 64) {
        float4 c0 = c4[2 * k], c1 = c4[2 * k + 1];
        float b = bk[k];
        float f0 = fmaf(dot8(z0, c0, c1), 200.0f, b);
        float f1 = fmaf(dot8(z1, c0, c1), 200.0f, b);
        float x0 = f0 - m0;
        float x1 = f1 - m1;
        if (x0 > 0.0f) {               // new max (rare)
            float f = __expf(-x0);
            t0 = f * fmaf(-x0, sv0, t0);
            sv0 = fmaf(sv0, f, 1.0f);
            m0 = f0; i0 = k;
        } else if (x0 > -87.0f) {      // non-underflowing candidate (rare)
            float e = __expf(x0);
            sv0 += e;
            t0 = fmaf(x0, e, t0);
        }
        if (x1 > 0.0f) {
            float f = __expf(-x1);
            t1 = f * fmaf(-x1, sv1, t1);
            sv1 = fmaf(sv1, f, 1.0f);
            m1 = f1; i1 = k;
        } else if (x1 > -87.0f) {
            float e = __expf(x1);
            sv1 += e;
            t1 = fmaf(x1, e, t1);
        }
    }

    float entAcc = 0.0f, sqAcc = 0.0f;
#pragma unroll
    for (int r = 0; r < 2; ++r) {
        float mr = r ? m1 : m0, sr = r ? sv1 : sv0, tr = r ? t1 : t0;
        int ir = r ? i1 : i0;
        const float* zr = r ? z1 : z0;
        for (int off = 32; off > 0; off >>= 1) {
            float mo = __shfl_xor(mr, off);
            float so = __shfl_xor(sr, off);
            float to = __shfl_xor(tr, off);
            int   io = __shfl_xor(ir, off);
            float mn = fmaxf(mr, mo);
            float d1 = mr - mn, d2 = mo - mn;
            float f1 = __expf(d1), f2 = __expf(d2);   // one of them is exp(0)=1
            float tn = f1 * fmaf(d1, sr, tr) + f2 * fmaf(d2, so, to);
            float sn = f1 * sr + f2 * so;
            ir = (mr > mo) ? ir : ((mo > mr) ? io : (ir < io ? ir : io));
            mr = mn; sr = sn; tr = tn;
        }
        if (lane == 0) {
            int row = row0 + r;
            entAcc += tr / sr - logf(sr);
            am_out[row] = -mr;               // x_true = (200*dot+b) - m'
            rs_out[row] = 1.0f / sr;
            out_idx[row] = (float)ir;
            float4 q0 = c4[2 * ir], q1 = c4[2 * ir + 1];
            float qv[8] = {q0.x, q0.y, q0.z, q0.w, q1.x, q1.y, q1.z, q1.w};
            int bb = row >> 8, hw = row & 255;
            float* o = out_zq + bb * 2048 + hw;
#pragma unroll
            for (int c = 0; c < 8; ++c) {
                o[c * 256] = qv[c];
                float dq = qv[c] - zr[c];
                sqAcc += dq * dq;
            }
        }
    }
    // block-level reduce -> 1 atomic per scalar per block
    __shared__ float redSq[4], redEnt[4];
    if (lane == 0) { redSq[wave] = sqAcc; redEnt[wave] = entAcc; }
    __syncthreads();
    if (threadIdx.x == 0) {
        atomicAdd(&scal[0], redSq[0] + redSq[1] + redSq[2] + redSq[3]);
        atomicAdd(&scal[1], redEnt[0] + redEnt[1] + redEnt[2] + redEnt[3]);
    }
}

// ---------------- pass 2: avg_probs, k-major ----------------
// thread owns TWO k's; rows staged 512 at a time in LDS (broadcast reads).
__global__ __launch_bounds__(256) void pass2(
    const float* __restrict__ cb, const float* __restrict__ bk,
    const float* __restrict__ zt, const float* __restrict__ am,
    const float* __restrict__ rs, float* __restrict__ avgp)
{
    __shared__ float lz[512 * 8];
    __shared__ float lam[512];
    __shared__ float lrs[512];
    const int tid = threadIdx.x;
    const int kb = blockIdx.x & 31;          // 32 k-blocks of 512 codes
    const int rsp = blockIdx.x >> 5;         // 16 row splits
    const int row0 = rsp * 512;
    const int k0 = kb * 512 + tid, k1 = k0 + 256;

    const float4* zsrc = (const float4*)(zt + row0 * 8);
    float4* zdst = (float4*)lz;
#pragma unroll
    for (int i = 0; i < 4; ++i) zdst[tid + 256 * i] = zsrc[tid + 256 * i];
    for (int i = tid; i < 512; i += 256) { lam[i] = am[row0 + i]; lrs[i] = rs[row0 + i]; }
    __syncthreads();

    const float4* c4 = (const float4*)cb;
    float4 a0 = c4[2 * k0], a1 = c4[2 * k0 + 1];
    float4 b0 = c4[2 * k1], b1 = c4[2 * k1 + 1];
    float bb0 = bk[k0], bb1 = bk[k1];
    float acc0 = 0.0f, acc1 = 0.0f;
#pragma unroll 2
    for (int n = 0; n < 512; ++n) {
        const float4* zp = (const float4*)(lz + n * 8);   // broadcast, conflict-free
        float4 v0 = zp[0], v1 = zp[1];
        float amn = lam[n], rn = lrs[n];
        float d0 = v0.x * a0.x + v0.y * a0.y + v0.z * a0.z + v0.w * a0.w
                 + v1.x * a1.x + v1.y * a1.y + v1.z * a1.z + v1.w * a1.w;
        float d1 = v0.x * b0.x + v0.y * b0.y + v0.z * b0.z + v0.w * b0.w
                 + v1.x * b1.x + v1.y * b1.y + v1.z * b1.z + v1.w * b1.w;
        float x0 = fmaf(d0, 200.0f, amn + bb0);           // flat - m_n
        float x1 = fmaf(d1, 200.0f, amn + bb1);
        if (x0 > -87.0f) acc0 = fmaf(__expf(x0), rn, acc0);  // rare
        if (x1 > -87.0f) acc1 = fmaf(__expf(x1), rn, acc1);
    }
    atomicAdd(&avgp[k0], acc0);
    atomicAdd(&avgp[k1], acc1);
}

// ---------------- finalize: avg entropy + loss assembly ----------------
__global__ __launch_bounds__(256) void finalize(
    const float* __restrict__ avgp, const float* __restrict__ scal,
    float* __restrict__ out_loss)
{
    float acc = 0.0f;
    for (int k = threadIdx.x; k < KCODES; k += 256) {
        float avg = avgp[k] * (1.0f / 8192.0f);
        acc += avg * logf(avg + 1e-5f);    // avg==0 contributes exactly 0
    }
#pragma unroll
    for (int off = 32; off > 0; off >>= 1) acc += __shfl_xor(acc, off);
    __shared__ float red[4];
    int wave = threadIdx.x >> 6, lane = threadIdx.x & 63;
    if (lane == 0) red[wave] = acc;
    __syncthreads();
    if (threadIdx.x == 0) {
        float T = red[0] + red[1] + red[2] + red[3];   // sum avg*log(avg+eps)
        // loss = 1.25*mean((zq-z)^2) + 0.1*(sample_entropy - avg_entropy)
        float loss = 1.25f * (scal[0] * (1.0f / 65536.0f))
                   + 0.1f * (T - scal[1] * (1.0f / 8192.0f));
        out_loss[0] = loss;
    }
}

extern "C" void kernel_launch(void* const* d_in, const int* in_sizes, int n_in,
                              void* d_out, int out_size, void* d_ws, size_t ws_size,
                              hipStream_t stream) {
    const float* z  = (const float*)d_in[0];   // [32,8,16,16]
    const float* cb = (const float*)d_in[1];   // [16384,8]
    float* out = (float*)d_out;
    float* ws  = (float*)d_ws;

    // workspace layout (floats)
    float* zt   = ws;                // 65536  : z transposed [n][8]
    float* am   = ws + 65536;        // 8192   : -m'_n
    float* rs   = ws + 73728;        // 8192   : 1/s_n
    float* bk   = ws + 81920;        // 16384  : -100*||e_k||^2
    float* avgp = ws + 98304;        // 16384  : sum_n p[n,k]
    float* scal = ws + 114688;       // 2      : [sq, entS]

    float* out_zq   = out;           // 65536
    float* out_loss = out + 65536;   // 1
    float* out_idx  = out + 65537;   // 8192

    hipMemsetAsync(avgp, 0, (16384 + 2) * sizeof(float), stream);

    prep_z <<<32,   256, 0, stream>>>(z, zt);
    prep_cb<<<64,   256, 0, stream>>>(cb, bk);
    pass1  <<<1024, 256, 0, stream>>>(cb, bk, zt, am, rs, out_zq, out_idx, scal);
    pass2  <<<512,  256, 0, stream>>>(cb, bk, zt, am, rs, avgp);
    finalize<<<1,   256, 0, stream>>>(avgp, scal, out_loss);
}

// Round 3
// 215.756 us; speedup vs baseline: 2.2803x; 1.2665x over previous
//
#include <hip/hip_runtime.h>
#include <math.h>

// VQ-VAE quantize: z [32,8,16,16] f32, codebook [16384,8] f32
// N=8192 rows, K=16384 codes, D=8.
// Outputs (concatenated f32): z_q [65536], loss [1], idx-as-float [8192].
//
// f[n,k] = 200*dot(z_n,e_k) - 100*||e_k||^2  (= -d/T + row const; softmax &
// argmax shift-invariant). exp underflows for f - m < -87 (matches fp32 ref).
//
// R2 lesson: predicated rare-paths bloated the inner loop ~4x (341 cyc/iter
// vs ~50 ideal). Now: hot loop = 8 FMA + 1 cmp per row per k; rare work
// (max update + candidate recording) behind a wave-uniform __any branch.
// Candidates (k, f) recorded to LDS; softmax stats + avg_probs computed from
// the recorded few at the end -> pass2's full N*K sweep is eliminated.

#define KCODES 16384
#define CAP 192

__device__ __forceinline__ float dot8s(const float* zr, float4 c0, float4 c1,
                                       float b) {
    float a = fmaf(zr[0], c0.x, b);
    a = fmaf(zr[1], c0.y, a);
    a = fmaf(zr[2], c0.z, a);
    a = fmaf(zr[3], c0.w, a);
    a = fmaf(zr[4], c1.x, a);
    a = fmaf(zr[5], c1.y, a);
    a = fmaf(zr[6], c1.z, a);
    a = fmaf(zr[7], c1.w, a);
    return a;
}

// ---------------- prep: codebook norms ----------------
__global__ __launch_bounds__(256) void prep_cb(const float* __restrict__ cb,
                                               float* __restrict__ bk) {
    int k = blockIdx.x * 256 + threadIdx.x;
    const float4* c4 = (const float4*)cb;
    float4 c0 = c4[2 * k], c1 = c4[2 * k + 1];
    float nrm = c0.x * c0.x + c0.y * c0.y + c0.z * c0.z + c0.w * c0.w
              + c1.x * c1.x + c1.y * c1.y + c1.z * c1.z + c1.w * c1.w;
    bk[k] = -100.0f * nrm;
}

// ---------------- pass 1: single sweep, candidate recording ----------------
// wave = 2 rows, lane strides K by 64. Grid 1024 blocks (8 rows/block).
__global__ __launch_bounds__(256, 4) void pass1(
    const float* __restrict__ z, const float* __restrict__ cb,
    const float* __restrict__ bk, float* __restrict__ mrow,
    int* __restrict__ flag, float* __restrict__ out_zq,
    float* __restrict__ out_idx, float* __restrict__ scal,
    float* __restrict__ avgp)
{
    __shared__ float wfb[8][CAP];
    __shared__ int   wkb[8][CAP];
    __shared__ int   cnt[8];
    __shared__ float redSq[4], redEnt[4];

    const int wave = threadIdx.x >> 6;
    const int lane = threadIdx.x & 63;
    const int w2 = wave * 2;
    const int row0 = blockIdx.x * 8 + w2;

    // load 2 rows (broadcast) and fold the 200x scale in
    float za[8], zb[8];
    {
        int b0 = row0 >> 8, hw0 = row0 & 255;
        int b1 = (row0 + 1) >> 8, hw1 = (row0 + 1) & 255;
        const float* p0 = z + b0 * 2048 + hw0;
        const float* p1 = z + b1 * 2048 + hw1;
#pragma unroll
        for (int c = 0; c < 8; ++c) {
            za[c] = 200.0f * p0[c * 256];
            zb[c] = 200.0f * p1[c * 256];
        }
    }
    if (lane == 0) { cnt[w2] = 0; cnt[w2 + 1] = 0; }
    __syncthreads();

    const float4* c4 = (const float4*)cb;
    float m0 = -3.4e38f, m1 = -3.4e38f;

    // warm-up: 512 codes, max only (no recording), then share
#pragma unroll 4
    for (int j = 0; j < 8; ++j) {
        int k = lane + 64 * j;
        float4 c0 = c4[2 * k], c1 = c4[2 * k + 1];
        float b = bk[k];
        m0 = fmaxf(m0, dot8s(za, c0, c1, b));
        m1 = fmaxf(m1, dot8s(zb, c0, c1, b));
    }
#pragma unroll
    for (int off = 32; off; off >>= 1) {
        m0 = fmaxf(m0, __shfl_xor(m0, off));
        m1 = fmaxf(m1, __shfl_xor(m1, off));
    }
    float mt0 = m0 - 87.0f, mt1 = m1 - 87.0f;

    // main sweep over all K: 8 FMA + 1 cmp per row per k fast path
    for (int j0 = 0; j0 < 256; j0 += 16) {
#pragma unroll
        for (int jj = 0; jj < 16; ++jj) {
            int k = lane + 64 * (j0 + jj);
            float4 c0 = c4[2 * k], c1 = c4[2 * k + 1];
            float b = bk[k];
            float f0 = dot8s(za, c0, c1, b);
            float f1 = dot8s(zb, c0, c1, b);
            bool h0 = f0 > mt0;
            bool h1 = f1 > mt1;
            if (__any(h0 || h1)) {          // wave-uniform, rare
                if (h0) {
                    m0 = fmaxf(m0, f0); mt0 = m0 - 87.0f;
                    int s_ = atomicAdd(&cnt[w2], 1);
                    if (s_ < CAP) { wfb[w2][s_] = f0; wkb[w2][s_] = k; }
                }
                if (h1) {
                    m1 = fmaxf(m1, f1); mt1 = m1 - 87.0f;
                    int s_ = atomicAdd(&cnt[w2 + 1], 1);
                    if (s_ < CAP) { wfb[w2 + 1][s_] = f1; wkb[w2 + 1][s_] = k; }
                }
            }
        }
        // tighten every lane's threshold to the wave-global running max
#pragma unroll
        for (int off = 32; off; off >>= 1) {
            m0 = fmaxf(m0, __shfl_xor(m0, off));
            m1 = fmaxf(m1, __shfl_xor(m1, off));
        }
        mt0 = m0 - 87.0f; mt1 = m1 - 87.0f;
    }
    __syncthreads();   // drain this wave's LDS atomics/writes before reads

    // flush: per row, compute s, t, argmin, entropy, avg_probs from candidates
    float entAcc = 0.0f, sqAcc = 0.0f;
#pragma unroll
    for (int r = 0; r < 2; ++r) {
        const int br = w2 + r;
        const int row = row0 + r;
        const float m = r ? m1 : m0;
        const float* zs = r ? zb : za;
        int c = cnt[br];
        if (c > CAP) {                       // overflow: defer to fixup
            if (lane == 0) { flag[row] = 1; mrow[row] = m; }
            continue;
        }
        float sl = 0.0f, tl = 0.0f;
        int kmin = 0x7fffffff;
        for (int i = lane; i < c; i += 64) {
            float x = wfb[br][i] - m;        // <= 0; == 0 at the argmax
            float e = 0.0f;
            if (x > -87.0f) {
                e = __expf(x);
                sl += e;
                tl = fmaf(x, e, tl);
                if (x == 0.0f) kmin = min(kmin, wkb[br][i]);
            }
            wfb[br][i] = e;                  // stash e for the flush loop
        }
#pragma unroll
        for (int off = 32; off; off >>= 1) {
            sl += __shfl_xor(sl, off);
            tl += __shfl_xor(tl, off);
            kmin = min(kmin, __shfl_xor(kmin, off));
        }
        float rs = 1.0f / sl;
        for (int i = lane; i < c; i += 64) {
            float e = wfb[br][i];
            if (e != 0.0f) atomicAdd(&avgp[wkb[br][i]], e * rs);
        }
        if (lane == 0) {
            entAcc += tl * rs - logf(sl);
            out_idx[row] = (float)kmin;
            float4 q0 = c4[2 * kmin], q1 = c4[2 * kmin + 1];
            float qv[8] = {q0.x, q0.y, q0.z, q0.w, q1.x, q1.y, q1.z, q1.w};
            int bb = row >> 8, hw = row & 255;
            const float* zr = z + bb * 2048 + hw;   // raw row (L1-hot)
            float* o = out_zq + bb * 2048 + hw;
#pragma unroll
            for (int ch = 0; ch < 8; ++ch) {
                float raw = zr[ch * 256];
                o[ch * 256] = qv[ch];
                float dq = qv[ch] - raw;
                sqAcc += dq * dq;
            }
        }
    }
    if (lane == 0) { redSq[wave] = sqAcc; redEnt[wave] = entAcc; }
    __syncthreads();
    if (threadIdx.x == 0) {
        atomicAdd(&scal[0], redSq[0] + redSq[1] + redSq[2] + redSq[3]);
        atomicAdd(&scal[1], redEnt[0] + redEnt[1] + redEnt[2] + redEnt[3]);
    }
}

// ---------------- fixup: full serial recompute for overflowed rows ----------
// Dead code in practice (CAP=192 >> typical ~20 candidates); correctness net.
__global__ __launch_bounds__(256) void fixup(
    const float* __restrict__ z, const float* __restrict__ cb,
    const float* __restrict__ bk, const float* __restrict__ mrow,
    const int* __restrict__ flag, float* __restrict__ avgp,
    float* __restrict__ out_zq, float* __restrict__ out_idx,
    float* __restrict__ scal)
{
    int n = blockIdx.x * 256 + threadIdx.x;
    if (n >= 8192 || flag[n] == 0) return;
    float zraw[8], zs[8];
    int bb = n >> 8, hw = n & 255;
#pragma unroll
    for (int c = 0; c < 8; ++c) {
        zraw[c] = z[bb * 2048 + c * 256 + hw];
        zs[c] = 200.0f * zraw[c];
    }
    const float4* c4 = (const float4*)cb;
    float m = mrow[n];
    float s = 0.0f, t = 0.0f;
    int kmin = 0x7fffffff;
    for (int k = 0; k < KCODES; ++k) {
        float f = dot8s(zs, c4[2 * k], c4[2 * k + 1], bk[k]);
        float x = f - m;
        if (x > -87.0f) {
            float e = __expf(x);
            s += e; t = fmaf(x, e, t);
            if (x == 0.0f) kmin = min(kmin, k);
        }
    }
    float rs = 1.0f / s;
    for (int k = 0; k < KCODES; ++k) {
        float f = dot8s(zs, c4[2 * k], c4[2 * k + 1], bk[k]);
        float x = f - m;
        if (x > -87.0f) atomicAdd(&avgp[k], __expf(x) * rs);
    }
    out_idx[n] = (float)kmin;
    float sq = 0.0f;
#pragma unroll
    for (int c = 0; c < 8; ++c) {
        float q = cb[kmin * 8 + c];
        out_zq[bb * 2048 + c * 256 + hw] = q;
        float dq = q - zraw[c];
        sq += dq * dq;
    }
    atomicAdd(&scal[0], sq);
    atomicAdd(&scal[1], t * rs - logf(s));
}

// ---------------- finalize: avg entropy + loss assembly ----------------
__global__ __launch_bounds__(256) void finalize(
    const float* __restrict__ avgp, const float* __restrict__ scal,
    float* __restrict__ out_loss)
{
    float acc = 0.0f;
    for (int k = threadIdx.x; k < KCODES; k += 256) {
        float avg = avgp[k] * (1.0f / 8192.0f);
        acc += avg * logf(avg + 1e-5f);    // avg==0 contributes exactly 0
    }
#pragma unroll
    for (int off = 32; off > 0; off >>= 1) acc += __shfl_xor(acc, off);
    __shared__ float red[4];
    int wave = threadIdx.x >> 6, lane = threadIdx.x & 63;
    if (lane == 0) red[wave] = acc;
    __syncthreads();
    if (threadIdx.x == 0) {
        float T = red[0] + red[1] + red[2] + red[3];   // sum avg*log(avg+eps)
        // loss = 1.25*mean((zq-z)^2) + 0.1*(sample_entropy - avg_entropy)
        float loss = 1.25f * (scal[0] * (1.0f / 65536.0f))
                   + 0.1f * (T - scal[1] * (1.0f / 8192.0f));
        out_loss[0] = loss;
    }
}

extern "C" void kernel_launch(void* const* d_in, const int* in_sizes, int n_in,
                              void* d_out, int out_size, void* d_ws, size_t ws_size,
                              hipStream_t stream) {
    const float* z  = (const float*)d_in[0];   // [32,8,16,16]
    const float* cb = (const float*)d_in[1];   // [16384,8]
    float* out = (float*)d_out;
    float* ws  = (float*)d_ws;

    // workspace layout (floats)
    float* bk   = ws;                // 16384 : -100*||e_k||^2
    float* avgp = ws + 16384;        // 16384 : sum_n p[n,k]
    float* scal = ws + 32768;        // 2     : [sq, entS]  (+6 pad)
    int*   flag = (int*)(ws + 32776);// 8192  : overflow flags
    float* mrow = ws + 40968;        // 8192  : m for flagged rows

    float* out_zq   = out;           // 65536
    float* out_loss = out + 65536;   // 1
    float* out_idx  = out + 65537;   // 8192

    // zero avgp + scal + pad + flags (ws is re-poisoned to 0xAA every launch)
    hipMemsetAsync(avgp, 0, (16384 + 8 + 8192) * sizeof(float), stream);

    prep_cb <<<64,   256, 0, stream>>>(cb, bk);
    pass1   <<<1024, 256, 0, stream>>>(z, cb, bk, mrow, flag, out_zq, out_idx,
                                       scal, avgp);
    fixup   <<<32,   256, 0, stream>>>(z, cb, bk, mrow, flag, avgp, out_zq,
                                       out_idx, scal);
    finalize<<<1,    256, 0, stream>>>(avgp, scal, out_loss);
}